// Round 7
// baseline (193.864 us; speedup 1.0000x reference)
//
#include <hip/hip_runtime.h>
#include <hip/hip_bf16.h>

#define DM 512
#define NTOK 1024
#define NB 16

typedef _Float16 f16;
typedef _Float16 half8 __attribute__((ext_vector_type(8)));
typedef _Float16 half4_t __attribute__((ext_vector_type(4)));
typedef float f32x4 __attribute__((ext_vector_type(4)));

__device__ __forceinline__ void gload16(const void* g, void* l) {
    __builtin_amdgcn_global_load_lds(
        (const __attribute__((address_space(1))) void*)g,
        (__attribute__((address_space(3))) void*)l, 16, 0, 0);
}

// ---------------- transpose + convert: x f32 [B][C][N] -> xt f16 [B][N][C] ----------------
// float4 loads (16B/lane), half4 stores (8B/lane)
__global__ __launch_bounds__(256)
void transpose_x_kernel(const float* __restrict__ x, f16* __restrict__ xt) {
    __shared__ float tile[32][33];   // tile[c][n]
    int b = blockIdx.z;
    int n0 = blockIdx.x * 32, c0 = blockIdx.y * 32;
    int tx = threadIdx.x, ty = threadIdx.y;  // 8 x 32
    const float* xb = x + (size_t)b * DM * NTOK + (size_t)(c0 + ty) * NTOK + n0 + tx * 4;
    float4 v = *(const float4*)xb;
    tile[ty][tx * 4 + 0] = v.x; tile[ty][tx * 4 + 1] = v.y;
    tile[ty][tx * 4 + 2] = v.z; tile[ty][tx * 4 + 3] = v.w;
    __syncthreads();
    half4_t h = {(f16)tile[tx * 4 + 0][ty], (f16)tile[tx * 4 + 1][ty],
                 (f16)tile[tx * 4 + 2][ty], (f16)tile[tx * 4 + 3][ty]};
    *(half4_t*)&xt[(size_t)b * NTOK * DM + (size_t)(n0 + ty) * DM + c0 + tx * 4] = h;
}

// concat-convert Wq,Wk,Wv -> wqkvh [1536][512] f16, plus bias concat -> bqkv f32[1536]
__global__ __launch_bounds__(256)
void convert_wqkv_kernel(const float* __restrict__ Wq, const float* __restrict__ Wk,
                         const float* __restrict__ Wv, const float* __restrict__ bq,
                         const float* __restrict__ bk, const float* __restrict__ bv,
                         f16* __restrict__ dst, float* __restrict__ bdst) {
    int i = blockIdx.x * 256 + threadIdx.x;  // 0..786431
    int row = i >> 9, col = i & 511;
    float v = (row < 512) ? Wq[i] : (row < 1024) ? Wk[(row - 512) * 512 + col]
                                                 : Wv[(row - 1024) * 512 + col];
    dst[i] = (f16)v;
    if (i < 1536)
        bdst[i] = (i < 512) ? bq[i] : (i < 1024) ? bk[i - 512] : bv[i - 1024];
}

__global__ __launch_bounds__(256)
void convert_w_kernel(const float* __restrict__ src, f16* __restrict__ dst, int n) {
    int i = blockIdx.x * 256 + threadIdx.x;
    if (i < n) dst[i] = (f16)src[i];
}

// vtok [B][N][512] token-major -> vh [B][512][N] channel-major, half4 both sides
__global__ __launch_bounds__(256)
void transpose_v_kernel(const f16* __restrict__ vtok, f16* __restrict__ vh) {
    __shared__ f16 tile[32][36];     // tile[n][c]
    int b = blockIdx.z;
    int n0 = blockIdx.x * 32, c0 = blockIdx.y * 32;
    int tx = threadIdx.x, ty = threadIdx.y;  // 8 x 32
    const f16* src = vtok + (size_t)b * NTOK * DM + (size_t)(n0 + ty) * DM + c0 + tx * 4;
    half4_t v = *(const half4_t*)src;
    tile[ty][tx * 4 + 0] = v[0]; tile[ty][tx * 4 + 1] = v[1];
    tile[ty][tx * 4 + 2] = v[2]; tile[ty][tx * 4 + 3] = v[3];
    __syncthreads();
    half4_t h = {tile[tx * 4 + 0][ty], tile[tx * 4 + 1][ty],
                 tile[tx * 4 + 2][ty], tile[tx * 4 + 3][ty]};
    *(half4_t*)&vh[(size_t)b * DM * NTOK + (size_t)(c0 + ty) * NTOK + n0 + tx * 4] = h;
}

// ---------------- NT GEMM: D[i][j] = sum_k A[i][k]*B[j][k], 128x128 tile, 4 waves ----------------
// Proven round-4 K-loop (single buffer, 2 barriers). MODE:
// 0: QKV — gj<1024: f16 qk=D+bias[gj]; gj>=1024: f16 vtok[z][gi][gj-1024]=D+bias[gj]
// 2: scores — e=exp(min(D*scale,14)-4) -> f16 e-slot (upper 2KB of attn row) + rowsum atomics
// 3: out-proj — f32 out0 = D + bias[gi] + resid; then fused finalize: expand e16 -> normalized
//    f32 attn for this block's exclusive 32-row chunk (e16 dead after PV; rows block-owned)
// 5: PV — f16 out = D * (1/rowsum[gi])
template<int MODE, int KC>
__global__ __launch_bounds__(256)
void gemm_nt(const f16* __restrict__ A, const f16* __restrict__ B, void* __restrict__ Cout,
             const float* __restrict__ bias, const float* __restrict__ resid,
             f16* __restrict__ aux, float* __restrict__ rowsum, float* __restrict__ fin,
             int ldA, int ldB, int ldC,
             long sA, long sB, long sC, long sR, float scale) {
    __shared__ f16 As[128 * 32];
    __shared__ f16 Bs[128 * 32];
    int z = blockIdx.z;
    const f16* Ab = A + (size_t)z * sA;
    const f16* Bb = B + (size_t)z * sB;
    int tid = threadIdx.x;
    int wave = tid >> 6, lane = tid & 63;
    int wr = wave >> 1, wc = wave & 1;
    int tI = blockIdx.y * 128, tJ = blockIdx.x * 128;

    f32x4 acc[4][4];
#pragma unroll
    for (int m = 0; m < 4; ++m)
#pragma unroll
        for (int n = 0; n < 4; ++n) acc[m][n] = (f32x4){0.f, 0.f, 0.f, 0.f};

    int frow = lane & 15, fk = (lane >> 4) * 8;   // fragment addressing
    int sr = lane >> 2, sc = (lane & 3) * 8;      // staging addressing

    for (int k0 = 0; k0 < KC; k0 += 32) {
#pragma unroll
        for (int h = 0; h < 2; ++h) {
            int chunk = wave * 2 + h;             // 0..7, 16 rows each
            int r = chunk * 16 + sr;
            const f16* ga = Ab + (size_t)(tI + r) * ldA + k0 + sc;
            const f16* gb = Bb + (size_t)(tJ + r) * ldB + k0 + sc;
            gload16(ga, &As[chunk * 512 + lane * 8]);
            gload16(gb, &Bs[chunk * 512 + lane * 8]);
        }
        asm volatile("s_waitcnt vmcnt(0)" ::: "memory");
        __syncthreads();

        half8 af[4], bf[4];
#pragma unroll
        for (int m = 0; m < 4; ++m)
            af[m] = *(const half8*)&As[(wr * 64 + m * 16 + frow) * 32 + fk];
#pragma unroll
        for (int n = 0; n < 4; ++n)
            bf[n] = *(const half8*)&Bs[(wc * 64 + n * 16 + frow) * 32 + fk];
#pragma unroll
        for (int m = 0; m < 4; ++m)
#pragma unroll
            for (int n = 0; n < 4; ++n)
                acc[m][n] = __builtin_amdgcn_mfma_f32_16x16x32_f16(af[m], bf[n], acc[m][n], 0, 0, 0);
        __syncthreads();
    }

    // epilogue: D row = (lane>>4)*4 + r, col = lane&15  (verified m89 mapping)
    int ro = (lane >> 4) * 4, co = lane & 15;
#pragma unroll
    for (int m = 0; m < 4; ++m) {
#pragma unroll
        for (int r = 0; r < 4; ++r) {
            int gi = tI + wr * 64 + m * 16 + ro + r;
            float rs = 0.f, inv = 0.f;
            if (MODE == 5) inv = 1.0f / rowsum[z * 1024 + gi];
#pragma unroll
            for (int n = 0; n < 4; ++n) {
                int gj = tJ + wc * 64 + n * 16 + co;
                float v = acc[m][n][r];
                if (MODE == 0) {
                    v += bias[gj];
                    if (gj < 1024)   // block-uniform branch (tile never straddles 1024)
                        ((f16*)Cout)[(size_t)z * sC + (size_t)gi * ldC + gj] = (f16)v;
                    else             // V token-major, coalesced
                        aux[(size_t)z * 524288 + (size_t)gi * 512 + (gj - 1024)] = (f16)v;
                } else if (MODE == 2) {
                    float e = __expf(fminf(v * scale, 14.f) - 4.f);
                    // e-slot: f16 in the upper 2KB of attn row gi's 4KB slot
                    ((f16*)Cout)[((size_t)z * 1024 + gi) * 2048 + 1024 + gj] = (f16)e;
                    rs += e;
                } else if (MODE == 3) {
                    ((float*)Cout)[(size_t)z * sC + (size_t)gi * ldC + gj] =
                        v + bias[gi] + resid[(size_t)z * sR + (size_t)gi * ldC + gj];
                } else {  // MODE 5
                    ((f16*)Cout)[(size_t)z * sC + (size_t)gi * ldC + gj] = (f16)(v * inv);
                }
            }
            if (MODE == 2) {
                rs += __shfl_xor(rs, 1, 16);
                rs += __shfl_xor(rs, 2, 16);
                rs += __shfl_xor(rs, 4, 16);
                rs += __shfl_xor(rs, 8, 16);
                if ((lane & 15) == 0) atomicAdd(&rowsum[z * 1024 + gi], rs);
            }
        }
    }

    // ---- fused finalize (out-proj only): this block owns 32 exclusive attn rows ----
    if (MODE == 3) {
        int rowbase = (blockIdx.y * 8 + blockIdx.x) * 32;   // gridDim (8,4): 32 chunks x 32 rows
        half8 ev[16];
#pragma unroll
        for (int it = 0; it < 16; ++it) {
            int flat = it * 2048 + tid * 8;                 // [32 rows][1024 cols]
            int row = rowbase + (flat >> 10), col = flat & 1023;
            ev[it] = *(const half8*)((const f16*)fin + ((size_t)z * 1024 + row) * 2048 + 1024 + col);
        }
        __syncthreads();   // all e16 reads done before any f32 overwrite (in-place, block-owned rows)
#pragma unroll
        for (int it = 0; it < 16; ++it) {
            int flat = it * 2048 + tid * 8;
            int row = rowbase + (flat >> 10), col = flat & 1023;
            float inv = 1.0f / rowsum[z * 1024 + row];
            float* dst = fin + ((size_t)z * 1024 + row) * 1024 + col;
            float4 o0 = {(float)ev[it][0] * inv, (float)ev[it][1] * inv,
                         (float)ev[it][2] * inv, (float)ev[it][3] * inv};
            float4 o1 = {(float)ev[it][4] * inv, (float)ev[it][5] * inv,
                         (float)ev[it][6] * inv, (float)ev[it][7] * inv};
            *(float4*)dst = o0;
            *(float4*)(dst + 4) = o1;
        }
    }
}

extern "C" void kernel_launch(void* const* d_in, const int* in_sizes, int n_in,
                              void* d_out, int out_size, void* d_ws, size_t ws_size,
                              hipStream_t stream) {
    const float* x  = (const float*)d_in[0];
    const float* Wq = (const float*)d_in[1];
    const float* bq = (const float*)d_in[2];
    const float* Wk = (const float*)d_in[3];
    const float* bk = (const float*)d_in[4];
    const float* Wv = (const float*)d_in[5];
    const float* bv = (const float*)d_in[6];
    const float* Wo = (const float*)d_in[7];
    const float* bo = (const float*)d_in[8];

    float* out0 = (float*)d_out;                           // [16][512][1024] (32 MB)
    float* attn = (float*)d_out + (size_t)NB * DM * NTOK;  // [16][1024][1024] f32 (+e16 slots)

    // workspace layout (f16 units), peak 34,376,704 units = 68.75 MB (proven budget)
    f16* ws    = (f16*)d_ws;
    f16* xt    = ws;                        // [B][N][512]   8,388,608 (dead after QKV)
    f16* oh    = ws;                        // [B][N][512]   alias of xt
    f16* qk    = ws + 8388608;              // [B][N][1024] 16,777,216 (q cols 0..511, k cols 512..1023)
    f16* vh    = ws + 25165824;             // [B][512][N]   8,388,608
    f16* wqkvh = ws + 33554432;             // [1536][512]     786,432
    f16* woh   = ws + 33554432;             // [512][512]    alias of wqkvh
    float* bqkv   = (float*)(ws + 34340864);  // [1536] f32
    float* rowsum = (float*)(ws + 34343936);  // [16384] f32

    // vtok lives in the out0 region of d_out (dead until the final GEMM; consumed by transpose_v)
    f16* vtok = (f16*)out0;                 // [B][N][512] f16 = 16 MB of out0's 32 MB

    const long sTok   = (long)NTOK * DM;      // 524288
    const long sQK    = (long)NTOK * 1024;    // 1048576
    const long sEslot = (long)NTOK * 2048;    // 2097152 (f16 units per batch of e-slot rows)
    const float scal = 0.044194173824159216f;  // 1/sqrt(512)

    hipMemsetAsync(rowsum, 0, 16384 * sizeof(float), stream);
    transpose_x_kernel<<<dim3(32, 16, NB), dim3(8, 32), 0, stream>>>(x, xt);
    convert_wqkv_kernel<<<3072, 256, 0, stream>>>(Wq, Wk, Wv, bq, bk, bv, wqkvh, bqkv);

    // fused QKV: q,k -> qk[b][tok][0..1023]; V -> vtok[b][tok][0..511] (all coalesced)
    gemm_nt<0, 512><<<dim3(12, 8, NB), 256, 0, stream>>>(xt, wqkvh, qk, bqkv, nullptr,
        vtok, nullptr, nullptr, 512, 512, 1024, sTok, 0, sQK, 0, 0.f);

    // Wo convert AFTER QKV GEMM (woh aliases wqkvh)
    convert_w_kernel<<<1024, 256, 0, stream>>>(Wo, woh, 262144);
    // vtok -> vh channel-major (must precede out-proj which overwrites out0)
    transpose_v_kernel<<<dim3(32, 16, NB), dim3(8, 32), 0, stream>>>(vtok, vh);

    // scores: e = exp(min(s*scal,14)-4) -> f16 e-slots in d_out attn region + rowsum atomics
    gemm_nt<2, 512><<<dim3(8, 8, NB), 256, 0, stream>>>(qk, qk + 512, attn, nullptr, nullptr,
        nullptr, rowsum, nullptr, 1024, 1024, 0, sQK, sQK, 0, 0, scal);

    // PV: O = (e·V^T)·inv_l -> oh [B][N][512] f16   (e-slots still intact during PV)
    gemm_nt<5, 1024><<<dim3(4, 8, NB), 256, 0, stream>>>((const f16*)attn + 1024, vh, oh,
        nullptr, nullptr, nullptr, rowsum, nullptr, 2048, 1024, 512, sEslot, sTok, sTok, 0, 0.f);

    // out0 = Wo·O^T + bo + x, with fused finalize (e16 -> normalized f32 attn, block-owned rows)
    gemm_nt<3, 512><<<dim3(8, 4, NB), 256, 0, stream>>>(woh, oh, out0, bo, x,
        nullptr, rowsum, attn, 512, 512, 1024, 0, sTok, sTok, sTok, 0.f);
}

// Round 8
// 171.707 us; speedup vs baseline: 1.1290x; 1.1290x over previous
//
#include <hip/hip_runtime.h>
#include <hip/hip_bf16.h>

#define DM 512
#define NTOK 1024
#define NB 16

typedef _Float16 f16;
typedef _Float16 half8 __attribute__((ext_vector_type(8)));
typedef _Float16 half4_t __attribute__((ext_vector_type(4)));
typedef float f32x4 __attribute__((ext_vector_type(4)));

__device__ __forceinline__ void gload16(const void* g, void* l) {
    __builtin_amdgcn_global_load_lds(
        (const __attribute__((address_space(1))) void*)g,
        (__attribute__((address_space(3))) void*)l, 16, 0, 0);
}

// ---------------- transpose + convert: x f32 [B][C][N] -> xt f16 [B][N][C] ----------------
__global__ __launch_bounds__(256)
void transpose_x_kernel(const float* __restrict__ x, f16* __restrict__ xt) {
    __shared__ float tile[32][33];   // tile[c][n]
    int b = blockIdx.z;
    int n0 = blockIdx.x * 32, c0 = blockIdx.y * 32;
    int tx = threadIdx.x, ty = threadIdx.y;  // 8 x 32
    const float* xb = x + (size_t)b * DM * NTOK + (size_t)(c0 + ty) * NTOK + n0 + tx * 4;
    float4 v = *(const float4*)xb;
    tile[ty][tx * 4 + 0] = v.x; tile[ty][tx * 4 + 1] = v.y;
    tile[ty][tx * 4 + 2] = v.z; tile[ty][tx * 4 + 3] = v.w;
    __syncthreads();
    half4_t h = {(f16)tile[tx * 4 + 0][ty], (f16)tile[tx * 4 + 1][ty],
                 (f16)tile[tx * 4 + 2][ty], (f16)tile[tx * 4 + 3][ty]};
    *(half4_t*)&xt[(size_t)b * NTOK * DM + (size_t)(n0 + ty) * DM + c0 + tx * 4] = h;
}

// concat-convert Wq,Wk,Wv -> wqkvh [1536][512] f16, bias concat -> bqkv, rowsum zeroing
__global__ __launch_bounds__(256)
void convert_wqkv_kernel(const float* __restrict__ Wq, const float* __restrict__ Wk,
                         const float* __restrict__ Wv, const float* __restrict__ bq,
                         const float* __restrict__ bk, const float* __restrict__ bv,
                         f16* __restrict__ dst, float* __restrict__ bdst,
                         float* __restrict__ rowsum) {
    int i = blockIdx.x * 256 + threadIdx.x;  // 0..786431
    int row = i >> 9, col = i & 511;
    float v = (row < 512) ? Wq[i] : (row < 1024) ? Wk[(row - 512) * 512 + col]
                                                 : Wv[(row - 1024) * 512 + col];
    dst[i] = (f16)v;
    if (i < 1536)
        bdst[i] = (i < 512) ? bq[i] : (i < 1024) ? bk[i - 512] : bv[i - 1024];
    if (blockIdx.x < 64) rowsum[blockIdx.x * 256 + threadIdx.x] = 0.f;  // 16384 f32
}

__global__ __launch_bounds__(256)
void convert_w_kernel(const float* __restrict__ src, f16* __restrict__ dst, int n) {
    int i = blockIdx.x * 256 + threadIdx.x;
    if (i < n) dst[i] = (f16)src[i];
}

// vtok [B][N][512] token-major -> vh [B][512][N] channel-major, half4 both sides
__global__ __launch_bounds__(256)
void transpose_v_kernel(const f16* __restrict__ vtok, f16* __restrict__ vh) {
    __shared__ f16 tile[32][36];     // tile[n][c]
    int b = blockIdx.z;
    int n0 = blockIdx.x * 32, c0 = blockIdx.y * 32;
    int tx = threadIdx.x, ty = threadIdx.y;  // 8 x 32
    const f16* src = vtok + (size_t)b * NTOK * DM + (size_t)(n0 + ty) * DM + c0 + tx * 4;
    half4_t v = *(const half4_t*)src;
    tile[ty][tx * 4 + 0] = v[0]; tile[ty][tx * 4 + 1] = v[1];
    tile[ty][tx * 4 + 2] = v[2]; tile[ty][tx * 4 + 3] = v[3];
    __syncthreads();
    half4_t h = {tile[tx * 4 + 0][ty], tile[tx * 4 + 1][ty],
                 tile[tx * 4 + 2][ty], tile[tx * 4 + 3][ty]};
    *(half4_t*)&vh[(size_t)b * DM * NTOK + (size_t)(c0 + ty) * NTOK + n0 + tx * 4] = h;
}

// ---------------- NT GEMM: D[i][j] = sum_k A[i][k]*B[j][k], 128x128 tile, 4 waves ----------------
// BK=64: half the vmcnt(0)+barrier drains of BK=32 (the 2-phase structure's dominant stall,
// m233). LDS 32 KB single-buffer: occupancy still VGPR-bound at 4 blocks/CU (m69), unchanged.
// Bank conflicts at 128B row stride fixed by both-sides XOR swizzle (m201/m231): linear LDS
// dest, global source column pre-swizzled (slot ^ (row&7)), same XOR on fragment reads.
// MODE 0: QKV — gj<1024: f16 qk=D+bias[gj]; gj>=1024: f16 vtok[z][gi][gj-1024]=D+bias[gj]
// MODE 2: scores — e=exp(min(D*scale,14)-4) -> f16 e-slot (upper 2KB of attn row) + rowsum atomics
// MODE 3: out-proj — f32 out0 = D + bias[gi] + resid
// MODE 5: PV — f16 out = D * (1/rowsum[gi])
template<int MODE, int KC>
__global__ __launch_bounds__(256)
void gemm_nt(const f16* __restrict__ A, const f16* __restrict__ B, void* __restrict__ Cout,
             const float* __restrict__ bias, const float* __restrict__ resid,
             f16* __restrict__ aux, float* __restrict__ rowsum,
             int ldA, int ldB, int ldC,
             long sA, long sB, long sC, long sR, float scale) {
    __shared__ f16 As[128 * 64];
    __shared__ f16 Bs[128 * 64];
    int z = blockIdx.z;
    const f16* Ab = A + (size_t)z * sA;
    const f16* Bb = B + (size_t)z * sB;
    int tid = threadIdx.x;
    int wave = tid >> 6, lane = tid & 63;
    int wr = wave >> 1, wc = wave & 1;
    int tI = blockIdx.y * 128, tJ = blockIdx.x * 128;

    f32x4 acc[4][4];
#pragma unroll
    for (int m = 0; m < 4; ++m)
#pragma unroll
        for (int n = 0; n < 4; ++n) acc[m][n] = (f32x4){0.f, 0.f, 0.f, 0.f};

    int frow = lane & 15, fks = lane >> 4;   // fragment row-low, 16B-slot base

    for (int k0 = 0; k0 < KC; k0 += 64) {
        // STAGE: 1024 16B-slots each for A,B; linear LDS dest, source col inverse-swizzled
#pragma unroll
        for (int h = 0; h < 4; ++h) {
            int L = h * 256 + tid;           // slot 0..1023
            int r = L >> 3;                  // row 0..127
            int gc = ((L & 7) ^ (r & 7)) * 8;
            gload16(Ab + (size_t)(tI + r) * ldA + k0 + gc, &As[L * 8]);
            gload16(Bb + (size_t)(tJ + r) * ldB + k0 + gc, &Bs[L * 8]);
        }
        asm volatile("s_waitcnt vmcnt(0)" ::: "memory");
        __syncthreads();

#pragma unroll
        for (int ks = 0; ks < 2; ++ks) {
            half8 af[4], bf[4];
            int s = ks * 4 + fks;            // natural 16B-slot 0..7
#pragma unroll
            for (int m = 0; m < 4; ++m) {
                int R = wr * 64 + m * 16 + frow;
                af[m] = *(const half8*)&As[R * 64 + ((s ^ (R & 7)) << 3)];
            }
#pragma unroll
            for (int n = 0; n < 4; ++n) {
                int R = wc * 64 + n * 16 + frow;
                bf[n] = *(const half8*)&Bs[R * 64 + ((s ^ (R & 7)) << 3)];
            }
#pragma unroll
            for (int m = 0; m < 4; ++m)
#pragma unroll
                for (int n = 0; n < 4; ++n)
                    acc[m][n] = __builtin_amdgcn_mfma_f32_16x16x32_f16(af[m], bf[n], acc[m][n], 0, 0, 0);
        }
        __syncthreads();
    }

    // epilogue: D row = (lane>>4)*4 + r, col = lane&15  (verified m89 mapping)
    int ro = (lane >> 4) * 4, co = lane & 15;
#pragma unroll
    for (int m = 0; m < 4; ++m) {
#pragma unroll
        for (int r = 0; r < 4; ++r) {
            int gi = tI + wr * 64 + m * 16 + ro + r;
            float rs = 0.f, inv = 0.f;
            if (MODE == 5) inv = 1.0f / rowsum[z * 1024 + gi];
#pragma unroll
            for (int n = 0; n < 4; ++n) {
                int gj = tJ + wc * 64 + n * 16 + co;
                float v = acc[m][n][r];
                if (MODE == 0) {
                    v += bias[gj];
                    if (gj < 1024)   // block-uniform branch (tile never straddles 1024)
                        ((f16*)Cout)[(size_t)z * sC + (size_t)gi * ldC + gj] = (f16)v;
                    else             // V token-major, coalesced
                        aux[(size_t)z * 524288 + (size_t)gi * 512 + (gj - 1024)] = (f16)v;
                } else if (MODE == 2) {
                    float e = __expf(fminf(v * scale, 14.f) - 4.f);
                    // e-slot: f16 in the upper 2KB of attn row gi's 4KB slot
                    ((f16*)Cout)[((size_t)z * 1024 + gi) * 2048 + 1024 + gj] = (f16)e;
                    rs += e;
                } else if (MODE == 3) {
                    ((float*)Cout)[(size_t)z * sC + (size_t)gi * ldC + gj] =
                        v + bias[gi] + resid[(size_t)z * sR + (size_t)gi * ldC + gj];
                } else {  // MODE 5
                    ((f16*)Cout)[(size_t)z * sC + (size_t)gi * ldC + gj] = (f16)(v * inv);
                }
            }
            if (MODE == 2) {
                rs += __shfl_xor(rs, 1, 16);
                rs += __shfl_xor(rs, 2, 16);
                rs += __shfl_xor(rs, 4, 16);
                rs += __shfl_xor(rs, 8, 16);
                if ((lane & 15) == 0) atomicAdd(&rowsum[z * 1024 + gi], rs);
            }
        }
    }
}

// ---------------- finalize: attn[row][:] f32 = e16[row][:] * inv_l, in place ----------------
__global__ __launch_bounds__(256)
void finalize_attn(float* __restrict__ attn, const float* __restrict__ rowsum) {
    size_t row = blockIdx.x;
    float inv = 1.0f / rowsum[row];
    float* prow = attn + row * 1024;
    half4_t h = *(const half4_t*)((const f16*)prow + 1024 + threadIdx.x * 4);
    __syncthreads();
    float4 o = {(float)h[0] * inv, (float)h[1] * inv, (float)h[2] * inv, (float)h[3] * inv};
    ((float4*)prow)[threadIdx.x] = o;
}

extern "C" void kernel_launch(void* const* d_in, const int* in_sizes, int n_in,
                              void* d_out, int out_size, void* d_ws, size_t ws_size,
                              hipStream_t stream) {
    const float* x  = (const float*)d_in[0];
    const float* Wq = (const float*)d_in[1];
    const float* bq = (const float*)d_in[2];
    const float* Wk = (const float*)d_in[3];
    const float* bk = (const float*)d_in[4];
    const float* Wv = (const float*)d_in[5];
    const float* bv = (const float*)d_in[6];
    const float* Wo = (const float*)d_in[7];
    const float* bo = (const float*)d_in[8];

    float* out0 = (float*)d_out;                           // [16][512][1024]
    float* attn = (float*)d_out + (size_t)NB * DM * NTOK;  // [16][1024][1024] f32 (+e16 slots)

    // workspace layout (f16 units), peak 34,376,704 units = 68.75 MB (proven budget)
    f16* ws    = (f16*)d_ws;
    f16* xt    = ws;                        // [B][N][512]   8,388,608 (dead after QKV)
    f16* oh    = ws;                        // [B][N][512]   alias of xt
    f16* qk    = ws + 8388608;              // [B][N][1024] 16,777,216 (q cols 0..511, k cols 512..1023)
    f16* vh    = ws + 25165824;             // [B][512][N]   8,388,608
    f16* wqkvh = ws + 33554432;             // [1536][512]     786,432
    f16* woh   = ws + 33554432;             // [512][512]    alias of wqkvh
    float* bqkv   = (float*)(ws + 34340864);  // [1536] f32
    float* rowsum = (float*)(ws + 34343936);  // [16384] f32

    // vtok lives in the out0 region of d_out (dead until the final GEMM; consumed by transpose_v)
    f16* vtok = (f16*)out0;                 // [B][N][512] f16 = 16 MB of out0's 32 MB

    const long sTok   = (long)NTOK * DM;      // 524288
    const long sQK    = (long)NTOK * 1024;    // 1048576
    const long sEslot = (long)NTOK * 2048;    // 2097152 (f16 units per batch of e-slot rows)
    const float scal = 0.044194173824159216f;  // 1/sqrt(512)

    transpose_x_kernel<<<dim3(32, 16, NB), dim3(8, 32), 0, stream>>>(x, xt);
    convert_wqkv_kernel<<<3072, 256, 0, stream>>>(Wq, Wk, Wv, bq, bk, bv, wqkvh, bqkv, rowsum);

    // fused QKV: q,k -> qk[b][tok][0..1023]; V -> vtok[b][tok][0..511] (all coalesced)
    gemm_nt<0, 512><<<dim3(12, 8, NB), 256, 0, stream>>>(xt, wqkvh, qk, bqkv, nullptr,
        vtok, nullptr, 512, 512, 1024, sTok, 0, sQK, 0, 0.f);

    // Wo convert AFTER QKV GEMM (woh aliases wqkvh)
    convert_w_kernel<<<1024, 256, 0, stream>>>(Wo, woh, 262144);
    // vtok -> vh channel-major (must precede out-proj which overwrites out0)
    transpose_v_kernel<<<dim3(32, 16, NB), dim3(8, 32), 0, stream>>>(vtok, vh);

    // scores: e = exp(min(s*scal,14)-4) -> f16 e-slots in d_out attn region + rowsum atomics
    gemm_nt<2, 512><<<dim3(8, 8, NB), 256, 0, stream>>>(qk, qk + 512, attn, nullptr, nullptr,
        nullptr, rowsum, 1024, 1024, 0, sQK, sQK, 0, 0, scal);

    // PV: O = (e·V^T)·inv_l -> oh [B][N][512] f16   (MUST run before finalize destroys e-slots)
    gemm_nt<5, 1024><<<dim3(4, 8, NB), 256, 0, stream>>>((const f16*)attn + 1024, vh, oh,
        nullptr, nullptr, nullptr, rowsum, 2048, 1024, 512, sEslot, sTok, sTok, 0, 0.f);

    // finalize: expand e16 -> normalized f32 attn, in place
    finalize_attn<<<NB * NTOK, 256, 0, stream>>>(attn, rowsum);

    // out0 = Wo·O^T + bo + x
    gemm_nt<3, 512><<<dim3(8, 4, NB), 256, 0, stream>>>(woh, oh, out0, bo, x,
        nullptr, nullptr, 512, 512, 1024, 0, sTok, sTok, sTok, 0.f);
}

// Round 9
// 162.654 us; speedup vs baseline: 1.1919x; 1.0557x over previous
//
#include <hip/hip_runtime.h>
#include <hip/hip_bf16.h>

#define DM 512
#define NTOK 1024
#define NB 16

typedef _Float16 f16;
typedef _Float16 half8 __attribute__((ext_vector_type(8)));
typedef _Float16 half4_t __attribute__((ext_vector_type(4)));
typedef float f32x4 __attribute__((ext_vector_type(4)));

__device__ __forceinline__ void gload16(const void* g, void* l) {
    __builtin_amdgcn_global_load_lds(
        (const __attribute__((address_space(1))) void*)g,
        (__attribute__((address_space(3))) void*)l, 16, 0, 0);
}

// ---------------- transpose + convert: x f32 [B][C][N] -> xt f16 [B][N][C] ----------------
__global__ __launch_bounds__(256)
void transpose_x_kernel(const float* __restrict__ x, f16* __restrict__ xt) {
    __shared__ float tile[32][33];   // tile[c][n]
    int b = blockIdx.z;
    int n0 = blockIdx.x * 32, c0 = blockIdx.y * 32;
    int tx = threadIdx.x, ty = threadIdx.y;  // 8 x 32
    const float* xb = x + (size_t)b * DM * NTOK + (size_t)(c0 + ty) * NTOK + n0 + tx * 4;
    float4 v = *(const float4*)xb;
    tile[ty][tx * 4 + 0] = v.x; tile[ty][tx * 4 + 1] = v.y;
    tile[ty][tx * 4 + 2] = v.z; tile[ty][tx * 4 + 3] = v.w;
    __syncthreads();
    half4_t h = {(f16)tile[tx * 4 + 0][ty], (f16)tile[tx * 4 + 1][ty],
                 (f16)tile[tx * 4 + 2][ty], (f16)tile[tx * 4 + 3][ty]};
    *(half4_t*)&xt[(size_t)b * NTOK * DM + (size_t)(n0 + ty) * DM + c0 + tx * 4] = h;
}

// concat-convert Wq,Wk,Wv -> wqkvh [1536][512] f16, bias concat -> bqkv, rowsum zeroing
__global__ __launch_bounds__(256)
void convert_wqkv_kernel(const float* __restrict__ Wq, const float* __restrict__ Wk,
                         const float* __restrict__ Wv, const float* __restrict__ bq,
                         const float* __restrict__ bk, const float* __restrict__ bv,
                         f16* __restrict__ dst, float* __restrict__ bdst,
                         float* __restrict__ rowsum) {
    int i = blockIdx.x * 256 + threadIdx.x;  // 0..786431
    int row = i >> 9, col = i & 511;
    float v = (row < 512) ? Wq[i] : (row < 1024) ? Wk[(row - 512) * 512 + col]
                                                 : Wv[(row - 1024) * 512 + col];
    dst[i] = (f16)v;
    if (i < 1536)
        bdst[i] = (i < 512) ? bq[i] : (i < 1024) ? bk[i - 512] : bv[i - 1024];
    if (blockIdx.x < 64) rowsum[blockIdx.x * 256 + threadIdx.x] = 0.f;  // 16384 f32
}

__global__ __launch_bounds__(256)
void convert_w_kernel(const float* __restrict__ src, f16* __restrict__ dst, int n) {
    int i = blockIdx.x * 256 + threadIdx.x;
    if (i < n) dst[i] = (f16)src[i];
}

// vtok [B][N][512] token-major -> vh [B][512][N] channel-major, half4 both sides
__global__ __launch_bounds__(256)
void transpose_v_kernel(const f16* __restrict__ vtok, f16* __restrict__ vh) {
    __shared__ f16 tile[32][36];     // tile[n][c]
    int b = blockIdx.z;
    int n0 = blockIdx.x * 32, c0 = blockIdx.y * 32;
    int tx = threadIdx.x, ty = threadIdx.y;  // 8 x 32
    const f16* src = vtok + (size_t)b * NTOK * DM + (size_t)(n0 + ty) * DM + c0 + tx * 4;
    half4_t v = *(const half4_t*)src;
    tile[ty][tx * 4 + 0] = v[0]; tile[ty][tx * 4 + 1] = v[1];
    tile[ty][tx * 4 + 2] = v[2]; tile[ty][tx * 4 + 3] = v[3];
    __syncthreads();
    half4_t h = {tile[tx * 4 + 0][ty], tile[tx * 4 + 1][ty],
                 tile[tx * 4 + 2][ty], tile[tx * 4 + 3][ty]};
    *(half4_t*)&vh[(size_t)b * DM * NTOK + (size_t)(c0 + ty) * NTOK + n0 + tx * 4] = h;
}

// ---------------- NT GEMM: D[i][j] = sum_k A[i][k]*B[j][k], 128x128 tile, 4 waves ----------------
// BK=64 + both-sides XOR swizzle (proven round 8). NEW: T1 XCD-aware block swizzle —
// bijective chunked remap (all grids %8==0) so each XCD's private L2 gets contiguous
// work sharing the same batch/panel; converts ~900cy HBM misses into ~200cy L2 hits
// in this latency-bound regime (r3 counters: FETCH 68MB vs 18MB ideal, nothing busy).
// MODE 0: QKV — gj<1024: f16 qk=D+bias[gj]; gj>=1024: f16 vtok[z][gi][gj-1024]=D+bias[gj]
// MODE 2: scores — e=exp(min(D*scale,14)-4) -> f16 e-slot (upper 2KB of attn row) + rowsum atomics
// MODE 3: out-proj — f32 out0 = D + bias[gi] + resid
// MODE 5: PV — f16 out = D * (1/rowsum[gi])
template<int MODE, int KC>
__global__ __launch_bounds__(256)
void gemm_nt(const f16* __restrict__ A, const f16* __restrict__ B, void* __restrict__ Cout,
             const float* __restrict__ bias, const float* __restrict__ resid,
             f16* __restrict__ aux, float* __restrict__ rowsum,
             int ldA, int ldB, int ldC,
             long sA, long sB, long sC, long sR, float scale) {
    __shared__ f16 As[128 * 64];
    __shared__ f16 Bs[128 * 64];

    // T1: XCD-aware remap. flat%8 = XCD (round-robin dispatch); give each XCD a
    // contiguous chunk of work ids decoded x-fastest -> same-batch panels cluster per-L2.
    int gx = gridDim.x, gy = gridDim.y;
    int nwg = gx * gy * (int)gridDim.z;
    int flat = blockIdx.x + gx * (blockIdx.y + gy * blockIdx.z);
    int w = (flat & 7) * (nwg >> 3) + (flat >> 3);
    int bx = w % gx, by = (w / gx) % gy, bz = w / (gx * gy);

    int z = bz;
    const f16* Ab = A + (size_t)z * sA;
    const f16* Bb = B + (size_t)z * sB;
    int tid = threadIdx.x;
    int wave = tid >> 6, lane = tid & 63;
    int wr = wave >> 1, wc = wave & 1;
    int tI = by * 128, tJ = bx * 128;

    f32x4 acc[4][4];
#pragma unroll
    for (int m = 0; m < 4; ++m)
#pragma unroll
        for (int n = 0; n < 4; ++n) acc[m][n] = (f32x4){0.f, 0.f, 0.f, 0.f};

    int frow = lane & 15, fks = lane >> 4;   // fragment row-low, 16B-slot base

    for (int k0 = 0; k0 < KC; k0 += 64) {
        // STAGE: 1024 16B-slots each for A,B; linear LDS dest, source col inverse-swizzled
#pragma unroll
        for (int h = 0; h < 4; ++h) {
            int L = h * 256 + tid;           // slot 0..1023
            int r = L >> 3;                  // row 0..127
            int gc = ((L & 7) ^ (r & 7)) * 8;
            gload16(Ab + (size_t)(tI + r) * ldA + k0 + gc, &As[L * 8]);
            gload16(Bb + (size_t)(tJ + r) * ldB + k0 + gc, &Bs[L * 8]);
        }
        asm volatile("s_waitcnt vmcnt(0)" ::: "memory");
        __syncthreads();

#pragma unroll
        for (int ks = 0; ks < 2; ++ks) {
            half8 af[4], bf[4];
            int s = ks * 4 + fks;            // natural 16B-slot 0..7
#pragma unroll
            for (int m = 0; m < 4; ++m) {
                int R = wr * 64 + m * 16 + frow;
                af[m] = *(const half8*)&As[R * 64 + ((s ^ (R & 7)) << 3)];
            }
#pragma unroll
            for (int n = 0; n < 4; ++n) {
                int R = wc * 64 + n * 16 + frow;
                bf[n] = *(const half8*)&Bs[R * 64 + ((s ^ (R & 7)) << 3)];
            }
#pragma unroll
            for (int m = 0; m < 4; ++m)
#pragma unroll
                for (int n = 0; n < 4; ++n)
                    acc[m][n] = __builtin_amdgcn_mfma_f32_16x16x32_f16(af[m], bf[n], acc[m][n], 0, 0, 0);
        }
        __syncthreads();
    }

    // epilogue: D row = (lane>>4)*4 + r, col = lane&15  (verified m89 mapping)
    int ro = (lane >> 4) * 4, co = lane & 15;
#pragma unroll
    for (int m = 0; m < 4; ++m) {
#pragma unroll
        for (int r = 0; r < 4; ++r) {
            int gi = tI + wr * 64 + m * 16 + ro + r;
            float rs = 0.f, inv = 0.f;
            if (MODE == 5) inv = 1.0f / rowsum[z * 1024 + gi];
#pragma unroll
            for (int n = 0; n < 4; ++n) {
                int gj = tJ + wc * 64 + n * 16 + co;
                float v = acc[m][n][r];
                if (MODE == 0) {
                    v += bias[gj];
                    if (gj < 1024)   // block-uniform branch (tile never straddles 1024)
                        ((f16*)Cout)[(size_t)z * sC + (size_t)gi * ldC + gj] = (f16)v;
                    else             // V token-major, coalesced
                        aux[(size_t)z * 524288 + (size_t)gi * 512 + (gj - 1024)] = (f16)v;
                } else if (MODE == 2) {
                    float e = __expf(fminf(v * scale, 14.f) - 4.f);
                    // e-slot: f16 in the upper 2KB of attn row gi's 4KB slot
                    ((f16*)Cout)[((size_t)z * 1024 + gi) * 2048 + 1024 + gj] = (f16)e;
                    rs += e;
                } else if (MODE == 3) {
                    ((float*)Cout)[(size_t)z * sC + (size_t)gi * ldC + gj] =
                        v + bias[gi] + resid[(size_t)z * sR + (size_t)gi * ldC + gj];
                } else {  // MODE 5
                    ((f16*)Cout)[(size_t)z * sC + (size_t)gi * ldC + gj] = (f16)(v * inv);
                }
            }
            if (MODE == 2) {
                rs += __shfl_xor(rs, 1, 16);
                rs += __shfl_xor(rs, 2, 16);
                rs += __shfl_xor(rs, 4, 16);
                rs += __shfl_xor(rs, 8, 16);
                if ((lane & 15) == 0) atomicAdd(&rowsum[z * 1024 + gi], rs);
            }
        }
    }
}

// ---------------- finalize: attn[row][:] f32 = e16[row][:] * inv_l, in place ----------------
__global__ __launch_bounds__(256)
void finalize_attn(float* __restrict__ attn, const float* __restrict__ rowsum) {
    size_t row = blockIdx.x;
    float inv = 1.0f / rowsum[row];
    float* prow = attn + row * 1024;
    half4_t h = *(const half4_t*)((const f16*)prow + 1024 + threadIdx.x * 4);
    __syncthreads();
    float4 o = {(float)h[0] * inv, (float)h[1] * inv, (float)h[2] * inv, (float)h[3] * inv};
    ((float4*)prow)[threadIdx.x] = o;
}

extern "C" void kernel_launch(void* const* d_in, const int* in_sizes, int n_in,
                              void* d_out, int out_size, void* d_ws, size_t ws_size,
                              hipStream_t stream) {
    const float* x  = (const float*)d_in[0];
    const float* Wq = (const float*)d_in[1];
    const float* bq = (const float*)d_in[2];
    const float* Wk = (const float*)d_in[3];
    const float* bk = (const float*)d_in[4];
    const float* Wv = (const float*)d_in[5];
    const float* bv = (const float*)d_in[6];
    const float* Wo = (const float*)d_in[7];
    const float* bo = (const float*)d_in[8];

    float* out0 = (float*)d_out;                           // [16][512][1024]
    float* attn = (float*)d_out + (size_t)NB * DM * NTOK;  // [16][1024][1024] f32 (+e16 slots)

    // workspace layout (f16 units), peak 34,376,704 units = 68.75 MB (proven budget)
    f16* ws    = (f16*)d_ws;
    f16* xt    = ws;                        // [B][N][512]   8,388,608 (dead after QKV)
    f16* oh    = ws;                        // [B][N][512]   alias of xt
    f16* qk    = ws + 8388608;              // [B][N][1024] 16,777,216 (q cols 0..511, k cols 512..1023)
    f16* vh    = ws + 25165824;             // [B][512][N]   8,388,608
    f16* wqkvh = ws + 33554432;             // [1536][512]     786,432
    f16* woh   = ws + 33554432;             // [512][512]    alias of wqkvh
    float* bqkv   = (float*)(ws + 34340864);  // [1536] f32
    float* rowsum = (float*)(ws + 34343936);  // [16384] f32

    // vtok lives in the out0 region of d_out (dead until the final GEMM; consumed by transpose_v)
    f16* vtok = (f16*)out0;                 // [B][N][512] f16 = 16 MB of out0's 32 MB

    const long sTok   = (long)NTOK * DM;      // 524288
    const long sQK    = (long)NTOK * 1024;    // 1048576
    const long sEslot = (long)NTOK * 2048;    // 2097152 (f16 units per batch of e-slot rows)
    const float scal = 0.044194173824159216f;  // 1/sqrt(512)

    transpose_x_kernel<<<dim3(32, 16, NB), dim3(8, 32), 0, stream>>>(x, xt);
    convert_wqkv_kernel<<<3072, 256, 0, stream>>>(Wq, Wk, Wv, bq, bk, bv, wqkvh, bqkv, rowsum);

    // fused QKV: q,k -> qk[b][tok][0..1023]; V -> vtok[b][tok][0..511] (all coalesced)
    gemm_nt<0, 512><<<dim3(12, 8, NB), 256, 0, stream>>>(xt, wqkvh, qk, bqkv, nullptr,
        vtok, nullptr, 512, 512, 1024, sTok, 0, sQK, 0, 0.f);

    // Wo convert AFTER QKV GEMM (woh aliases wqkvh)
    convert_w_kernel<<<1024, 256, 0, stream>>>(Wo, woh, 262144);
    // vtok -> vh channel-major (must precede out-proj which overwrites out0)
    transpose_v_kernel<<<dim3(32, 16, NB), dim3(8, 32), 0, stream>>>(vtok, vh);

    // scores: e = exp(min(s*scal,14)-4) -> f16 e-slots in d_out attn region + rowsum atomics
    gemm_nt<2, 512><<<dim3(8, 8, NB), 256, 0, stream>>>(qk, qk + 512, attn, nullptr, nullptr,
        nullptr, rowsum, 1024, 1024, 0, sQK, sQK, 0, 0, scal);

    // PV: O = (e·V^T)·inv_l -> oh [B][N][512] f16   (MUST run before finalize destroys e-slots)
    gemm_nt<5, 1024><<<dim3(4, 8, NB), 256, 0, stream>>>((const f16*)attn + 1024, vh, oh,
        nullptr, nullptr, nullptr, rowsum, 2048, 1024, 512, sEslot, sTok, sTok, 0, 0.f);

    // finalize: expand e16 -> normalized f32 attn, in place
    finalize_attn<<<NB * NTOK, 256, 0, stream>>>(attn, rowsum);

    // out0 = Wo·O^T + bo + x
    gemm_nt<3, 512><<<dim3(8, 4, NB), 256, 0, stream>>>(woh, oh, out0, bo, x,
        nullptr, nullptr, 512, 512, 1024, 0, sTok, sTok, sTok, 0.f);
}

// Round 10
// 154.322 us; speedup vs baseline: 1.2562x; 1.0540x over previous
//
#include <hip/hip_runtime.h>
#include <hip/hip_bf16.h>

#define DM 512
#define NTOK 1024
#define NB 16

typedef _Float16 f16;
typedef _Float16 half8 __attribute__((ext_vector_type(8)));
typedef _Float16 half4_t __attribute__((ext_vector_type(4)));
typedef float f32x4 __attribute__((ext_vector_type(4)));

__device__ __forceinline__ void gload16(const void* g, void* l) {
    __builtin_amdgcn_global_load_lds(
        (const __attribute__((address_space(1))) void*)g,
        (__attribute__((address_space(3))) void*)l, 16, 0, 0);
}

// ---------------- prep: transpose_x (blocks 0..8191) + convert_wqkv (8192..11263) ----------------
__global__ __launch_bounds__(256)
void prep_kernel(const float* __restrict__ x, f16* __restrict__ xt,
                 const float* __restrict__ Wq, const float* __restrict__ Wk,
                 const float* __restrict__ Wv, const float* __restrict__ bq,
                 const float* __restrict__ bk, const float* __restrict__ bv,
                 f16* __restrict__ wdst, float* __restrict__ bdst,
                 float* __restrict__ rowsum) {
    __shared__ float tile[32][33];
    int bid = blockIdx.x, tid = threadIdx.x;
    if (bid < 8192) {
        // transpose_x: x f32 [B][C][N] -> xt f16 [B][N][C]
        int b = bid >> 9, byy = (bid >> 5) & 15, bxx = bid & 31;
        int n0 = bxx * 32, c0 = byy * 32;
        int tx = tid & 7, ty = tid >> 3;   // 8 x 32
        const float* xb = x + (size_t)b * DM * NTOK + (size_t)(c0 + ty) * NTOK + n0 + tx * 4;
        float4 v = *(const float4*)xb;
        tile[ty][tx * 4 + 0] = v.x; tile[ty][tx * 4 + 1] = v.y;
        tile[ty][tx * 4 + 2] = v.z; tile[ty][tx * 4 + 3] = v.w;
        __syncthreads();
        half4_t h = {(f16)tile[tx * 4 + 0][ty], (f16)tile[tx * 4 + 1][ty],
                     (f16)tile[tx * 4 + 2][ty], (f16)tile[tx * 4 + 3][ty]};
        *(half4_t*)&xt[(size_t)b * NTOK * DM + (size_t)(n0 + ty) * DM + c0 + tx * 4] = h;
    } else {
        int c = bid - 8192;                // 0..3071
        int i = c * 256 + tid;             // 0..786431
        int row = i >> 9, col = i & 511;
        float v = (row < 512) ? Wq[i] : (row < 1024) ? Wk[(row - 512) * 512 + col]
                                                     : Wv[(row - 1024) * 512 + col];
        wdst[i] = (f16)v;
        if (i < 1536)
            bdst[i] = (i < 512) ? bq[i] : (i < 1024) ? bk[i - 512] : bv[i - 1024];
        if (c < 64) rowsum[c * 256 + tid] = 0.f;  // 16384 f32
    }
}

// ---------------- mid: convert_w (blocks 0..1023) + transpose_v (1024..9215) ----------------
__global__ __launch_bounds__(256)
void mid_kernel(const float* __restrict__ Wo, f16* __restrict__ woh,
                const f16* __restrict__ vtok, f16* __restrict__ vh) {
    __shared__ f16 tile[32][36];
    int bid = blockIdx.x, tid = threadIdx.x;
    if (bid < 1024) {
        int i = bid * 256 + tid;
        woh[i] = (f16)Wo[i];
    } else {
        int c = bid - 1024;                // 0..8191
        int b = c >> 9, byy = (c >> 5) & 15, bxx = c & 31;
        int n0 = bxx * 32, c0 = byy * 32;
        int tx = tid & 7, ty = tid >> 3;   // 8 x 32
        const f16* src = vtok + (size_t)b * NTOK * DM + (size_t)(n0 + ty) * DM + c0 + tx * 4;
        half4_t v = *(const half4_t*)src;
        tile[ty][tx * 4 + 0] = v[0]; tile[ty][tx * 4 + 1] = v[1];
        tile[ty][tx * 4 + 2] = v[2]; tile[ty][tx * 4 + 3] = v[3];
        __syncthreads();
        half4_t h = {tile[tx * 4 + 0][ty], tile[tx * 4 + 1][ty],
                     tile[tx * 4 + 2][ty], tile[tx * 4 + 3][ty]};
        *(half4_t*)&vh[(size_t)b * DM * NTOK + (size_t)(c0 + ty) * NTOK + n0 + tx * 4] = h;
    }
}

// ---------------- NT GEMM: D[i][j] = sum_k A[i][k]*B[j][k], 128x128 tile, 4 waves ----------------
// BK=64 + both-sides XOR swizzle (r8) + T1 XCD-aware bijective block remap (r9).
// Grid geometry is compile-time (GX,GY); launch is 1D flat with NWG = GX*GY*NB blocks.
// MODE 3 additionally launches XB extra blocks that run the finalize role (e16 -> normalized
// f32 attn, 8 exclusive rows/block) concurrently -- its streaming fills the GEMM's stall bubbles.
// MODE 0: QKV — gj<1024: f16 qk=D+bias[gj]; gj>=1024: f16 vtok[z][gi][gj-1024]=D+bias[gj]
// MODE 2: scores — e=exp(min(D*scale,14)-4) -> f16 e-slot (upper 2KB of attn row) + rowsum atomics
// MODE 3: out-proj — f32 out0 = D + bias[gi] + resid   (+ finalize role blocks)
// MODE 5: PV — f16 out = D * (1/rowsum[gi])
template<int MODE, int KC, int GX, int GY, int XB>
__global__ __launch_bounds__(256)
void gemm_nt(const f16* __restrict__ A, const f16* __restrict__ B, void* __restrict__ Cout,
             const float* __restrict__ bias, const float* __restrict__ resid,
             f16* __restrict__ aux, float* __restrict__ rowsum, float* __restrict__ fin,
             int ldA, int ldB, int ldC,
             long sA, long sB, long sC, long sR, float scale) {
    __shared__ f16 As[128 * 64];
    __shared__ f16 Bs[128 * 64];

    constexpr int NWG = GX * GY * NB;
    int flat = blockIdx.x;
    int tid = threadIdx.x;

    if (MODE == 3 && flat >= NWG) {
        // ---- finalize role: 8 exclusive attn rows; read-all -> sync -> write-all ----
        int row0 = (flat - NWG) * 8;
        const f16* eb = (const f16*)fin;
        half4_t h[8];
#pragma unroll
        for (int rr = 0; rr < 8; ++rr)
            h[rr] = *(const half4_t*)(eb + (size_t)(row0 + rr) * 2048 + 1024 + tid * 4);
        __syncthreads();
#pragma unroll
        for (int rr = 0; rr < 8; ++rr) {
            int row = row0 + rr;
            float inv = 1.0f / rowsum[row];
            float4 o = {(float)h[rr][0] * inv, (float)h[rr][1] * inv,
                        (float)h[rr][2] * inv, (float)h[rr][3] * inv};
            *(float4*)(fin + (size_t)row * 1024 + tid * 4) = o;
        }
        return;
    }

    // T1: XCD-aware bijective remap (NWG % 8 == 0 for all instantiations)
    int w = (flat & 7) * (NWG >> 3) + (flat >> 3);
    int bx = w % GX, by = (w / GX) % GY, bz = w / (GX * GY);

    int z = bz;
    const f16* Ab = A + (size_t)z * sA;
    const f16* Bb = B + (size_t)z * sB;
    int wave = tid >> 6, lane = tid & 63;
    int wr = wave >> 1, wc = wave & 1;
    int tI = by * 128, tJ = bx * 128;

    f32x4 acc[4][4];
#pragma unroll
    for (int m = 0; m < 4; ++m)
#pragma unroll
        for (int n = 0; n < 4; ++n) acc[m][n] = (f32x4){0.f, 0.f, 0.f, 0.f};

    int frow = lane & 15, fks = lane >> 4;   // fragment row-low, 16B-slot base

    for (int k0 = 0; k0 < KC; k0 += 64) {
        // STAGE: 1024 16B-slots each for A,B; linear LDS dest, source col inverse-swizzled
#pragma unroll
        for (int h = 0; h < 4; ++h) {
            int L = h * 256 + tid;           // slot 0..1023
            int r = L >> 3;                  // row 0..127
            int gc = ((L & 7) ^ (r & 7)) * 8;
            gload16(Ab + (size_t)(tI + r) * ldA + k0 + gc, &As[L * 8]);
            gload16(Bb + (size_t)(tJ + r) * ldB + k0 + gc, &Bs[L * 8]);
        }
        asm volatile("s_waitcnt vmcnt(0)" ::: "memory");
        __syncthreads();

#pragma unroll
        for (int ks = 0; ks < 2; ++ks) {
            half8 af[4], bf[4];
            int s = ks * 4 + fks;            // natural 16B-slot 0..7
#pragma unroll
            for (int m = 0; m < 4; ++m) {
                int R = wr * 64 + m * 16 + frow;
                af[m] = *(const half8*)&As[R * 64 + ((s ^ (R & 7)) << 3)];
            }
#pragma unroll
            for (int n = 0; n < 4; ++n) {
                int R = wc * 64 + n * 16 + frow;
                bf[n] = *(const half8*)&Bs[R * 64 + ((s ^ (R & 7)) << 3)];
            }
#pragma unroll
            for (int m = 0; m < 4; ++m)
#pragma unroll
                for (int n = 0; n < 4; ++n)
                    acc[m][n] = __builtin_amdgcn_mfma_f32_16x16x32_f16(af[m], bf[n], acc[m][n], 0, 0, 0);
        }
        __syncthreads();
    }

    // epilogue: D row = (lane>>4)*4 + r, col = lane&15  (verified m89 mapping)
    int ro = (lane >> 4) * 4, co = lane & 15;
#pragma unroll
    for (int m = 0; m < 4; ++m) {
#pragma unroll
        for (int r = 0; r < 4; ++r) {
            int gi = tI + wr * 64 + m * 16 + ro + r;
            float rs = 0.f, inv = 0.f;
            if (MODE == 5) inv = 1.0f / rowsum[z * 1024 + gi];
#pragma unroll
            for (int n = 0; n < 4; ++n) {
                int gj = tJ + wc * 64 + n * 16 + co;
                float v = acc[m][n][r];
                if (MODE == 0) {
                    v += bias[gj];
                    if (gj < 1024)   // block-uniform branch (tile never straddles 1024)
                        ((f16*)Cout)[(size_t)z * sC + (size_t)gi * ldC + gj] = (f16)v;
                    else             // V token-major, coalesced
                        aux[(size_t)z * 524288 + (size_t)gi * 512 + (gj - 1024)] = (f16)v;
                } else if (MODE == 2) {
                    float e = __expf(fminf(v * scale, 14.f) - 4.f);
                    // e-slot: f16 in the upper 2KB of attn row gi's 4KB slot
                    ((f16*)Cout)[((size_t)z * 1024 + gi) * 2048 + 1024 + gj] = (f16)e;
                    rs += e;
                } else if (MODE == 3) {
                    ((float*)Cout)[(size_t)z * sC + (size_t)gi * ldC + gj] =
                        v + bias[gi] + resid[(size_t)z * sR + (size_t)gi * ldC + gj];
                } else {  // MODE 5
                    ((f16*)Cout)[(size_t)z * sC + (size_t)gi * ldC + gj] = (f16)(v * inv);
                }
            }
            if (MODE == 2) {
                rs += __shfl_xor(rs, 1, 16);
                rs += __shfl_xor(rs, 2, 16);
                rs += __shfl_xor(rs, 4, 16);
                rs += __shfl_xor(rs, 8, 16);
                if ((lane & 15) == 0) atomicAdd(&rowsum[z * 1024 + gi], rs);
            }
        }
    }
}

extern "C" void kernel_launch(void* const* d_in, const int* in_sizes, int n_in,
                              void* d_out, int out_size, void* d_ws, size_t ws_size,
                              hipStream_t stream) {
    const float* x  = (const float*)d_in[0];
    const float* Wq = (const float*)d_in[1];
    const float* bq = (const float*)d_in[2];
    const float* Wk = (const float*)d_in[3];
    const float* bk = (const float*)d_in[4];
    const float* Wv = (const float*)d_in[5];
    const float* bv = (const float*)d_in[6];
    const float* Wo = (const float*)d_in[7];
    const float* bo = (const float*)d_in[8];

    float* out0 = (float*)d_out;                           // [16][512][1024]
    float* attn = (float*)d_out + (size_t)NB * DM * NTOK;  // [16][1024][1024] f32 (+e16 slots)

    // workspace layout (f16 units), peak 34,376,704 units = 68.75 MB (proven budget)
    f16* ws    = (f16*)d_ws;
    f16* xt    = ws;                        // [B][N][512]   8,388,608 (dead after QKV)
    f16* oh    = ws;                        // [B][N][512]   alias of xt
    f16* qk    = ws + 8388608;              // [B][N][1024] 16,777,216 (q cols 0..511, k cols 512..1023)
    f16* vh    = ws + 25165824;             // [B][512][N]   8,388,608
    f16* wqkvh = ws + 33554432;             // [1536][512]     786,432
    f16* woh   = ws + 33554432;             // [512][512]    alias of wqkvh
    float* bqkv   = (float*)(ws + 34340864);  // [1536] f32
    float* rowsum = (float*)(ws + 34343936);  // [16384] f32

    // vtok lives in the out0 region of d_out (dead until the final GEMM; consumed by mid_kernel)
    f16* vtok = (f16*)out0;                 // [B][N][512] f16 = 16 MB of out0's 32 MB

    const long sTok   = (long)NTOK * DM;      // 524288
    const long sQK    = (long)NTOK * 1024;    // 1048576
    const long sEslot = (long)NTOK * 2048;    // 2097152 (f16 units per batch of e-slot rows)
    const float scal = 0.044194173824159216f;  // 1/sqrt(512)

    // 1) prep: x transpose+convert, W_qkv concat-convert, bias concat, rowsum zero
    prep_kernel<<<8192 + 3072, 256, 0, stream>>>(x, xt, Wq, Wk, Wv, bq, bk, bv,
                                                 wqkvh, bqkv, rowsum);

    // 2) fused QKV: q,k -> qk[b][tok][0..1023]; V -> vtok[b][tok][0..511]
    gemm_nt<0, 512, 12, 8, 0><<<12 * 8 * NB, 256, 0, stream>>>(xt, wqkvh, qk, bqkv, nullptr,
        vtok, nullptr, nullptr, 512, 512, 1024, sTok, 0, sQK, 0, 0.f);

    // 3) mid: Wo convert (woh aliases dead wqkvh) + vtok -> vh channel-major
    mid_kernel<<<1024 + 8192, 256, 0, stream>>>(Wo, woh, vtok, vh);

    // 4) scores: e = exp(min(s*scal,14)-4) -> f16 e-slots in attn region + rowsum atomics
    gemm_nt<2, 512, 8, 8, 0><<<8 * 8 * NB, 256, 0, stream>>>(qk, qk + 512, attn, nullptr, nullptr,
        nullptr, rowsum, nullptr, 1024, 1024, 0, sQK, sQK, 0, 0, scal);

    // 5) PV: O = (e·V^T)·inv_l -> oh [B][N][512] f16   (e-slots read here, destroyed next)
    gemm_nt<5, 1024, 4, 8, 0><<<4 * 8 * NB, 256, 0, stream>>>((const f16*)attn + 1024, vh, oh,
        nullptr, nullptr, nullptr, rowsum, nullptr, 2048, 1024, 512, sEslot, sTok, sTok, 0, 0.f);

    // 6) out0 = Wo·O^T + bo + x, plus 2048 finalize-role blocks (e16 -> normalized f32 attn)
    gemm_nt<3, 512, 8, 4, 2048><<<8 * 4 * NB + 2048, 256, 0, stream>>>(woh, oh, out0, bo, x,
        nullptr, rowsum, attn, 512, 512, 1024, 0, sTok, sTok, sTok, 0.f);
}